// Round 1
// baseline (23024.538 us; speedup 1.0000x reference)
//
#include <hip/hip_runtime.h>
#include <hip/hip_bf16.h>
#include <math.h>

#define TCc 200
#define TDc 50
#define BATCH 256
#define Ec 300
#define Hc 512

__device__ __forceinline__ float sigf(float x) { return 1.f / (1.f + expf(-x)); }

__global__ __launch_bounds__(256) void zero_kernel(float* p, int n) {
  int i = blockIdx.x * 256 + threadIdx.x;
  if (i < n) p[i] = 0.f;
}

// One LSTM timestep: fused gathered-embedding input projection + recurrent GEMM + gates.
// Block tile: 32 batch rows x 16 units (x 4 gates = 64 weight columns).
// Grid: (BSZ/32, H/16). 256 threads; thread -> (u_l = tid&15, m_l = tid>>4), owns
// rows m_l and m_l+16 for unit u0+u_l, all four gates.
__global__ __launch_bounds__(256) void lstm_step_kernel(
    const float* __restrict__ emb,
    const int* __restrict__ idsA, const int* __restrict__ idsB,  // idsB null => all rows from idsA
    int T, int t,
    const float* __restrict__ Wih, const float* __restrict__ Whh,
    const float* __restrict__ bih, const float* __restrict__ bhh,
    const float* __restrict__ h_in, const float* __restrict__ c_in,
    float* __restrict__ h_out, float* __restrict__ c_out,
    float* __restrict__ feat,      // tok path: tanh(h) at [(b*T+t)*H+u]
    float* __restrict__ finals,    // desc path: tanh(h) at [b*H+u] when t==len-1
    const int* __restrict__ lenA, const int* __restrict__ lenB)
{
  const int b0 = blockIdx.x * 32;
  const int u0 = blockIdx.y * 16;
  const int tid = threadIdx.x;
  const int u_l = tid & 15;
  const int m_l = tid >> 4;  // 0..15

  __shared__ float As[32][17];
  __shared__ float Bs[4][16][17];
  __shared__ int rows[32];

  if (tid < 32) {
    int b = b0 + tid;
    int id;
    if (idsB == nullptr || b < BATCH) id = idsA[b * T + t];
    else id = idsB[(b - BATCH) * T + t];
    rows[tid] = id;
  }
  __syncthreads();

  float acc[2][4] = {{0.f, 0.f, 0.f, 0.f}, {0.f, 0.f, 0.f, 0.f}};

  // ---- phase 1: x @ Wih^T, K = E = 300 (last tile zero-padded) ----
  for (int k0 = 0; k0 < Ec; k0 += 16) {
    #pragma unroll
    for (int i = 0; i < 2; ++i) {
      int lin = tid + i * 256;
      int m = lin >> 4, kk = lin & 15;
      int k = k0 + kk;
      As[m][kk] = (k < Ec) ? emb[(size_t)rows[m] * Ec + k] : 0.f;
    }
    #pragma unroll
    for (int i = 0; i < 4; ++i) {
      int lin = tid + i * 256;
      int g = lin >> 8, rem = lin & 255;
      int u = rem >> 4, kk = rem & 15;
      int k = k0 + kk;
      Bs[g][u][kk] = (k < Ec) ? Wih[(size_t)(g * Hc + u0 + u) * Ec + k] : 0.f;
    }
    __syncthreads();
    #pragma unroll
    for (int kk = 0; kk < 16; ++kk) {
      float a0 = As[m_l][kk];
      float a1 = As[m_l + 16][kk];
      #pragma unroll
      for (int g = 0; g < 4; ++g) {
        float w = Bs[g][u_l][kk];
        acc[0][g] = fmaf(a0, w, acc[0][g]);
        acc[1][g] = fmaf(a1, w, acc[1][g]);
      }
    }
    __syncthreads();
  }

  // ---- phase 2: h @ Whh^T, K = H = 512 ----
  for (int k0 = 0; k0 < Hc; k0 += 16) {
    #pragma unroll
    for (int i = 0; i < 2; ++i) {
      int lin = tid + i * 256;
      int m = lin >> 4, kk = lin & 15;
      As[m][kk] = h_in[(size_t)(b0 + m) * Hc + k0 + kk];
    }
    #pragma unroll
    for (int i = 0; i < 4; ++i) {
      int lin = tid + i * 256;
      int g = lin >> 8, rem = lin & 255;
      int u = rem >> 4, kk = rem & 15;
      Bs[g][u][kk] = Whh[(size_t)(g * Hc + u0 + u) * Hc + k0 + kk];
    }
    __syncthreads();
    #pragma unroll
    for (int kk = 0; kk < 16; ++kk) {
      float a0 = As[m_l][kk];
      float a1 = As[m_l + 16][kk];
      #pragma unroll
      for (int g = 0; g < 4; ++g) {
        float w = Bs[g][u_l][kk];
        acc[0][g] = fmaf(a0, w, acc[0][g]);
        acc[1][g] = fmaf(a1, w, acc[1][g]);
      }
    }
    __syncthreads();
  }

  const int u = u0 + u_l;
  const float bi = bih[u]          + bhh[u];
  const float bf = bih[Hc + u]     + bhh[Hc + u];
  const float bg = bih[2 * Hc + u] + bhh[2 * Hc + u];
  const float bo = bih[3 * Hc + u] + bhh[3 * Hc + u];

  #pragma unroll
  for (int p = 0; p < 2; ++p) {
    int b = b0 + m_l + p * 16;
    float gi = sigf(acc[p][0] + bi);
    float gf = sigf(acc[p][1] + bf);
    float gg = tanhf(acc[p][2] + bg);
    float go = sigf(acc[p][3] + bo);
    float c_old = c_in[(size_t)b * Hc + u];
    float cn = gf * c_old + gi * gg;
    float hn = go * tanhf(cn);
    c_out[(size_t)b * Hc + u] = cn;
    h_out[(size_t)b * Hc + u] = hn;
    if (feat) feat[((size_t)b * T + t) * Hc + u] = tanhf(hn);
    if (finals) {
      int len = (b < BATCH) ? lenA[b] : lenB[b - BATCH];
      if (t == len - 1) finals[(size_t)b * Hc + u] = tanhf(hn);
    }
  }
}

// scores[m] = tanh(feat[m,:] @ attn_W^T + attn_b) . attnS_W + attnS_b, m in [0, B*TC)
// Block: 32 rows, loops n-tiles of 64 over N=512; fused reduction, no atomics.
__global__ __launch_bounds__(256) void attn_scores_kernel(
    const float* __restrict__ feat, const float* __restrict__ attn_W,
    const float* __restrict__ attn_b, const float* __restrict__ attnS_W,
    const float* __restrict__ attnS_b, float* __restrict__ scores)
{
  const int m0 = blockIdx.x * 32;
  const int tid = threadIdx.x;
  const int tn = tid & 15;
  const int tm = tid >> 4;

  __shared__ float As[32][17];
  __shared__ float Bs[64][17];
  __shared__ float red[32][16];

  float s0 = 0.f, s1 = 0.f;

  for (int n0 = 0; n0 < Hc; n0 += 64) {
    float acc[2][4] = {{0, 0, 0, 0}, {0, 0, 0, 0}};
    for (int k0 = 0; k0 < Hc; k0 += 16) {
      #pragma unroll
      for (int i = 0; i < 2; ++i) {
        int lin = tid + i * 256;
        int m = lin >> 4, kk = lin & 15;
        As[m][kk] = feat[(size_t)(m0 + m) * Hc + k0 + kk];
      }
      #pragma unroll
      for (int i = 0; i < 4; ++i) {
        int lin = tid + i * 256;
        int n = lin >> 4, kk = lin & 15;
        Bs[n][kk] = attn_W[(size_t)(n0 + n) * Hc + k0 + kk];
      }
      __syncthreads();
      #pragma unroll
      for (int kk = 0; kk < 16; ++kk) {
        float a0 = As[tm][kk], a1 = As[tm + 16][kk];
        #pragma unroll
        for (int jj = 0; jj < 4; ++jj) {
          float w = Bs[tn * 4 + jj][kk];
          acc[0][jj] = fmaf(a0, w, acc[0][jj]);
          acc[1][jj] = fmaf(a1, w, acc[1][jj]);
        }
      }
      __syncthreads();
    }
    #pragma unroll
    for (int jj = 0; jj < 4; ++jj) {
      int n = n0 + tn * 4 + jj;
      float sw = attnS_W[n];
      s0 += tanhf(acc[0][jj] + attn_b[n]) * sw;
      s1 += tanhf(acc[1][jj] + attn_b[n]) * sw;
    }
  }
  red[tm][tn] = s0;
  red[tm + 16][tn] = s1;
  __syncthreads();
  if (tid < 32) {
    float s = attnS_b[0];
    #pragma unroll
    for (int i = 0; i < 16; ++i) s += red[tid][i];
    scores[m0 + tid] = s;
  }
}

// Per-sample masked softmax over T=200 + weighted pooling of feat -> pooled (B,H)
__global__ __launch_bounds__(256) void softmax_pool_kernel(
    const float* __restrict__ scores, const int* __restrict__ tok_len,
    const float* __restrict__ feat, float* __restrict__ pooled)
{
  const int b = blockIdx.x;
  const int tid = threadIdx.x;
  __shared__ float w[TCc];
  __shared__ float red[256];
  const int len = tok_len[b];

  float myv = -1e30f;
  if (tid < TCc) {
    float s = scores[b * TCc + tid];
    myv = (tid < len) ? s : -1e9f;
    w[tid] = myv;
  }
  red[tid] = myv;
  __syncthreads();
  for (int s = 128; s > 0; s >>= 1) {
    if (tid < s) red[tid] = fmaxf(red[tid], red[tid + s]);
    __syncthreads();
  }
  const float mx = red[0];
  __syncthreads();
  float e = 0.f;
  if (tid < TCc) e = expf(w[tid] - mx);
  red[tid] = e;
  __syncthreads();
  for (int s = 128; s > 0; s >>= 1) {
    if (tid < s) red[tid] += red[tid + s];
    __syncthreads();
  }
  const float sum = red[0];
  __syncthreads();
  if (tid < TCc) w[tid] = e / sum;
  __syncthreads();

  for (int h = tid; h < Hc; h += 256) {
    float acc = 0.f;
    for (int t = 0; t < TCc; ++t)
      acc = fmaf(w[t], feat[((size_t)b * TCc + t) * Hc + h], acc);
    pooled[(size_t)b * Hc + h] = acc;
  }
}

// C[m,n] = tanh(A[m,:] . W[n,:] + bias[n]); grid (M/32, N/64)
__global__ __launch_bounds__(256) void gemm_bias_tanh_kernel(
    const float* __restrict__ A, const float* __restrict__ W,
    const float* __restrict__ bias, float* __restrict__ C, int N, int K)
{
  const int m0 = blockIdx.x * 32;
  const int n0 = blockIdx.y * 64;
  const int tid = threadIdx.x;
  const int tn = tid & 15;
  const int tm = tid >> 4;

  __shared__ float As[32][17];
  __shared__ float Bs[64][17];

  float acc[2][4] = {{0, 0, 0, 0}, {0, 0, 0, 0}};
  for (int k0 = 0; k0 < K; k0 += 16) {
    #pragma unroll
    for (int i = 0; i < 2; ++i) {
      int lin = tid + i * 256;
      int m = lin >> 4, kk = lin & 15;
      As[m][kk] = A[(size_t)(m0 + m) * K + k0 + kk];
    }
    #pragma unroll
    for (int i = 0; i < 4; ++i) {
      int lin = tid + i * 256;
      int n = lin >> 4, kk = lin & 15;
      Bs[n][kk] = W[(size_t)(n0 + n) * K + k0 + kk];
    }
    __syncthreads();
    #pragma unroll
    for (int kk = 0; kk < 16; ++kk) {
      float a0 = As[tm][kk], a1 = As[tm + 16][kk];
      #pragma unroll
      for (int jj = 0; jj < 4; ++jj) {
        float w = Bs[tn * 4 + jj][kk];
        acc[0][jj] = fmaf(a0, w, acc[0][jj]);
        acc[1][jj] = fmaf(a1, w, acc[1][jj]);
      }
    }
    __syncthreads();
  }
  #pragma unroll
  for (int jj = 0; jj < 4; ++jj) {
    int n = n0 + tn * 4 + jj;
    float b = bias[n];
    C[(size_t)(m0 + tm) * N + n]      = tanhf(acc[0][jj] + b);
    C[(size_t)(m0 + tm + 16) * N + n] = tanhf(acc[1][jj] + b);
  }
}

// Triplet cosine hinge loss, mean over 256 samples. One block, thread b = sample.
__global__ __launch_bounds__(256) void loss_kernel(
    const float* __restrict__ code, const float* __restrict__ finals, float* __restrict__ out)
{
  const int b = threadIdx.x;
  const float* cv = code + (size_t)b * Hc;
  const float* av = finals + (size_t)b * Hc;
  const float* nv = finals + (size_t)(BATCH + b) * Hc;
  float dca = 0, dcn = 0, ncc = 0, naa = 0, nnn = 0;
  for (int k = 0; k < Hc; ++k) {
    float c = cv[k], a = av[k], n = nv[k];
    dca = fmaf(c, a, dca);
    dcn = fmaf(c, n, dcn);
    ncc = fmaf(c, c, ncc);
    naa = fmaf(a, a, naa);
    nnn = fmaf(n, n, nnn);
  }
  float cos_a = dca / fmaxf(sqrtf(ncc) * sqrtf(naa), 1e-8f);
  float cos_n = dcn / fmaxf(sqrtf(ncc) * sqrtf(nnn), 1e-8f);
  float hinge = fmaxf(0.6f - cos_a + cos_n, 1e-6f);
  __shared__ float red[256];
  red[b] = hinge;
  __syncthreads();
  for (int s = 128; s > 0; s >>= 1) {
    if (b < s) red[b] += red[b + s];
    __syncthreads();
  }
  if (b == 0) out[0] = red[0] / 256.0f;
}

extern "C" void kernel_launch(void* const* d_in, const int* in_sizes, int n_in,
                              void* d_out, int out_size, void* d_ws, size_t ws_size,
                              hipStream_t stream) {
  const int* tokens          = (const int*)d_in[0];
  const int* tok_len         = (const int*)d_in[1];
  const int* desc_anchor     = (const int*)d_in[2];
  const int* desc_anchor_len = (const int*)d_in[3];
  const int* desc_neg        = (const int*)d_in[4];
  const int* desc_neg_len    = (const int*)d_in[5];
  const float* tok_emb  = (const float*)d_in[6];
  const float* tok_Wih  = (const float*)d_in[7];
  const float* tok_Whh  = (const float*)d_in[8];
  const float* tok_bih  = (const float*)d_in[9];
  const float* tok_bhh  = (const float*)d_in[10];
  const float* desc_emb = (const float*)d_in[11];
  const float* desc_Wih = (const float*)d_in[12];
  const float* desc_Whh = (const float*)d_in[13];
  const float* desc_bih = (const float*)d_in[14];
  const float* desc_bhh = (const float*)d_in[15];
  const float* attn_W   = (const float*)d_in[16];
  const float* attn_b   = (const float*)d_in[17];
  const float* attnS_W  = (const float*)d_in[18];
  const float* attnS_b  = (const float*)d_in[19];
  const float* out_W1   = (const float*)d_in[20];
  const float* out_b1   = (const float*)d_in[21];
  const float* out_W2   = (const float*)d_in[22];
  const float* out_b2   = (const float*)d_in[23];

  float* ws = (float*)d_ws;
  float* feat    = ws;                                   // 256*200*512 = 26,214,400
  float* zbase   = feat + (size_t)BATCH * TCc * Hc;
  float* h_tok0  = zbase;                                // 131072
  float* c_tok0  = h_tok0 + BATCH * Hc;                  // 131072
  float* h_desc0 = c_tok0 + BATCH * Hc;                  // 262144
  float* c_desc0 = h_desc0 + 2 * BATCH * Hc;             // 262144
  float* h_tok1  = c_desc0 + 2 * BATCH * Hc;
  float* c_tok1  = h_tok1 + BATCH * Hc;
  float* h_desc1 = c_tok1 + BATCH * Hc;
  float* c_desc1 = h_desc1 + 2 * BATCH * Hc;
  float* finals  = c_desc1 + 2 * BATCH * Hc;             // 2*256*512
  float* scores  = finals + 2 * BATCH * Hc;              // 256*200
  float* pooled  = scores + BATCH * TCc;                 // 256*512
  float* a2      = pooled + BATCH * Hc;                  // 256*512
  float* code    = a2 + BATCH * Hc;                      // 256*512

  const int zn = 2 * (BATCH * Hc) + 2 * (2 * BATCH * Hc);  // h_tok0,c_tok0,h_desc0,c_desc0
  zero_kernel<<<(zn + 255) / 256, 256, 0, stream>>>(zbase, zn);

  // token LSTM: 200 sequential steps, h/c ping-pong
  for (int t = 0; t < TCc; ++t) {
    float* hi = (t & 1) ? h_tok1 : h_tok0;
    float* ho = (t & 1) ? h_tok0 : h_tok1;
    float* ci = (t & 1) ? c_tok1 : c_tok0;
    float* co = (t & 1) ? c_tok0 : c_tok1;
    lstm_step_kernel<<<dim3(BATCH / 32, Hc / 16), 256, 0, stream>>>(
        tok_emb, tokens, nullptr, TCc, t, tok_Wih, tok_Whh, tok_bih, tok_bhh,
        hi, ci, ho, co, feat, nullptr, nullptr, nullptr);
  }
  // desc LSTM: anchor (rows 0..255) + neg (rows 256..511) batched
  for (int t = 0; t < TDc; ++t) {
    float* hi = (t & 1) ? h_desc1 : h_desc0;
    float* ho = (t & 1) ? h_desc0 : h_desc1;
    float* ci = (t & 1) ? c_desc1 : c_desc0;
    float* co = (t & 1) ? c_desc0 : c_desc1;
    lstm_step_kernel<<<dim3(2 * BATCH / 32, Hc / 16), 256, 0, stream>>>(
        desc_emb, desc_anchor, desc_neg, TDc, t, desc_Wih, desc_Whh, desc_bih, desc_bhh,
        hi, ci, ho, co, nullptr, finals, desc_anchor_len, desc_neg_len);
  }

  attn_scores_kernel<<<BATCH * TCc / 32, 256, 0, stream>>>(feat, attn_W, attn_b, attnS_W, attnS_b, scores);
  softmax_pool_kernel<<<BATCH, 256, 0, stream>>>(scores, tok_len, feat, pooled);
  gemm_bias_tanh_kernel<<<dim3(BATCH / 32, Hc / 64), 256, 0, stream>>>(pooled, out_W1, out_b1, a2, Hc, Hc);
  gemm_bias_tanh_kernel<<<dim3(BATCH / 32, Hc / 64), 256, 0, stream>>>(a2, out_W2, out_b2, code, Hc, Hc);
  loss_kernel<<<1, 256, 0, stream>>>(code, finals, (float*)d_out);
}

// Round 2
// 10205.590 us; speedup vs baseline: 2.2561x; 2.2561x over previous
//
#include <hip/hip_runtime.h>
#include <hip/hip_bf16.h>
#include <math.h>

#define TCc 200
#define TDc 50
#define BATCH 256
#define Ec 300
#define Hc 512
#define VOC 10000

__device__ __forceinline__ float sigf(float x) { return 1.f / (1.f + expf(-x)); }

__global__ __launch_bounds__(256) void zero_kernel(float* p, int n) {
  int i = blockIdx.x * 256 + threadIdx.x;
  if (i < n) p[i] = 0.f;
}

// ---------------- generic 64x64-tile GEMM: out = act(A @ Bw^T + bias) ----------------
// A: (M,K) row-major; Bw: (N,K) row-major; K arbitrary (zero-padded to 32), K%4==0.
// N % 64 == 0. Rows guarded for M not multiple of 64.
// ACT: 0 = none, 1 = tanh. REDUCE: fused tanh+dot with sW -> partial[blockIdx.y*M + r].
template<int ACT, int REDUCE>
__global__ __launch_bounds__(256) void gemm64_kernel(
    const float* __restrict__ A, const float* __restrict__ Bw,
    const float* __restrict__ bias, float* __restrict__ C,
    const float* __restrict__ sW, float* __restrict__ partial,
    int M, int N, int K)
{
  const int r0 = blockIdx.x * 64;
  const int n0 = blockIdx.y * 64;
  const int tid = threadIdx.x;
  const int tu = tid & 15;   // n-quad
  const int tm = tid >> 4;   // m-quad
  __shared__ float As[32][68];
  __shared__ float Bs[32][68];
  __shared__ float red[64][17];

  float acc[4][4] = {};
  const int nk = (K + 31) >> 5;
  for (int s = 0; s < nk; ++s) {
    const int k0 = s << 5;
    #pragma unroll
    for (int i = 0; i < 2; ++i) {
      int lin = tid + (i << 8);
      int kq = lin & 7, m = lin >> 3;  // m 0..63
      int k = k0 + (kq << 2);
      int r = r0 + m; if (r >= M) r = M - 1;
      float4 va = {0.f, 0.f, 0.f, 0.f}, vb = {0.f, 0.f, 0.f, 0.f};
      if (k < K) {
        va = *(const float4*)&A[(size_t)r * K + k];
        vb = *(const float4*)&Bw[(size_t)(n0 + m) * K + k];
      }
      As[(kq << 2) + 0][m] = va.x; As[(kq << 2) + 1][m] = va.y;
      As[(kq << 2) + 2][m] = va.z; As[(kq << 2) + 3][m] = va.w;
      Bs[(kq << 2) + 0][m] = vb.x; Bs[(kq << 2) + 1][m] = vb.y;
      Bs[(kq << 2) + 2][m] = vb.z; Bs[(kq << 2) + 3][m] = vb.w;
    }
    __syncthreads();
    #pragma unroll
    for (int kk = 0; kk < 32; ++kk) {
      float4 a = *(const float4*)&As[kk][tm << 2];
      float4 b = *(const float4*)&Bs[kk][tu << 2];
      acc[0][0] = fmaf(a.x, b.x, acc[0][0]); acc[0][1] = fmaf(a.x, b.y, acc[0][1]);
      acc[0][2] = fmaf(a.x, b.z, acc[0][2]); acc[0][3] = fmaf(a.x, b.w, acc[0][3]);
      acc[1][0] = fmaf(a.y, b.x, acc[1][0]); acc[1][1] = fmaf(a.y, b.y, acc[1][1]);
      acc[1][2] = fmaf(a.y, b.z, acc[1][2]); acc[1][3] = fmaf(a.y, b.w, acc[1][3]);
      acc[2][0] = fmaf(a.z, b.x, acc[2][0]); acc[2][1] = fmaf(a.z, b.y, acc[2][1]);
      acc[2][2] = fmaf(a.z, b.z, acc[2][2]); acc[2][3] = fmaf(a.z, b.w, acc[2][3]);
      acc[3][0] = fmaf(a.w, b.x, acc[3][0]); acc[3][1] = fmaf(a.w, b.y, acc[3][1]);
      acc[3][2] = fmaf(a.w, b.z, acc[3][2]); acc[3][3] = fmaf(a.w, b.w, acc[3][3]);
    }
    __syncthreads();
  }

  if (REDUCE) {
    float bj[4], wj[4];
    #pragma unroll
    for (int j = 0; j < 4; ++j) {
      int n = n0 + (tu << 2) + j;
      bj[j] = bias[n]; wj[j] = sW[n];
    }
    float p[4] = {0.f, 0.f, 0.f, 0.f};
    #pragma unroll
    for (int i = 0; i < 4; ++i)
      #pragma unroll
      for (int j = 0; j < 4; ++j)
        p[i] = fmaf(tanhf(acc[i][j] + bj[j]), wj[j], p[i]);
    #pragma unroll
    for (int i = 0; i < 4; ++i) red[(tm << 2) + i][tu] = p[i];
    __syncthreads();
    if (tid < 64) {
      int r = r0 + tid;
      if (r < M) {
        float s = 0.f;
        #pragma unroll
        for (int q = 0; q < 16; ++q) s += red[tid][q];
        partial[(size_t)blockIdx.y * M + r] = s;
      }
    }
  } else {
    float bj[4];
    #pragma unroll
    for (int j = 0; j < 4; ++j) bj[j] = bias ? bias[n0 + (tu << 2) + j] : 0.f;
    #pragma unroll
    for (int i = 0; i < 4; ++i) {
      int r = r0 + (tm << 2) + i;
      if (r < M) {
        float4 v;
        v.x = acc[i][0] + bj[0]; v.y = acc[i][1] + bj[1];
        v.z = acc[i][2] + bj[2]; v.w = acc[i][3] + bj[3];
        if (ACT) { v.x = tanhf(v.x); v.y = tanhf(v.y); v.z = tanhf(v.z); v.w = tanhf(v.w); }
        *(float4*)&C[(size_t)r * N + n0 + (tu << 2)] = v;
      }
    }
  }
}

// ---------------- one LSTM timestep ----------------
// tile: 32 batch rows x 16 units x 4 gates; 256 threads.
// thread: tu = tid&15 (unit), tm = tid>>4 (rows tm*2, tm*2+1); acc[2][4] = (row, gate).
// HAS_XPROJ: gates' input projection gathered from xproj (V,2048); else computed inline from emb/Wih.
template<int HAS_XPROJ>
__global__ __launch_bounds__(256) void lstm_step2_kernel(
    const float* __restrict__ xproj_or_emb, const float* __restrict__ Wih,
    const int* __restrict__ idsA, const int* __restrict__ idsB,
    int T, int t,
    const float* __restrict__ Whh,
    const float* __restrict__ bih, const float* __restrict__ bhh,
    const float* __restrict__ h_in, const float* __restrict__ c_in,
    float* __restrict__ h_out, float* __restrict__ c_out,
    float* __restrict__ feat, float* __restrict__ finals,
    const int* __restrict__ lenA, const int* __restrict__ lenB)
{
  const int b0 = blockIdx.x * 32;
  const int u0 = blockIdx.y * 16;
  const int tid = threadIdx.x;
  const int tu = tid & 15;
  const int tm = tid >> 4;

  __shared__ float As[32][34];   // [kk][m], m 0..31
  __shared__ float Bs[32][68];   // [kk][u*4+g]
  __shared__ int rows[32];

  float acc[2][4] = {};

  if (!HAS_XPROJ) {
    if (tid < 32) {
      int b = b0 + tid;
      rows[tid] = (idsB != nullptr && b >= BATCH) ? idsB[(b - BATCH) * T + t]
                                                  : idsA[b * T + t];
    }
    __syncthreads();
    // input projection inline: K = E = 300
    for (int k0 = 0; k0 < Ec; k0 += 32) {
      {
        int kq = tid & 7, m = tid >> 3;
        int k = k0 + (kq << 2);
        float4 va = {0.f, 0.f, 0.f, 0.f};
        if (k < Ec) va = *(const float4*)&xproj_or_emb[(size_t)rows[m] * Ec + k];
        As[(kq << 2) + 0][m] = va.x; As[(kq << 2) + 1][m] = va.y;
        As[(kq << 2) + 2][m] = va.z; As[(kq << 2) + 3][m] = va.w;
      }
      #pragma unroll
      for (int i = 0; i < 2; ++i) {
        int lin = tid + (i << 8);
        int kq = lin & 7, u = (lin >> 3) & 15, g = (lin >> 7) & 3;
        int k = k0 + (kq << 2);
        float4 vb = {0.f, 0.f, 0.f, 0.f};
        if (k < Ec) vb = *(const float4*)&Wih[(size_t)((g << 9) + u0 + u) * Ec + k];
        int col = (u << 2) + g;
        Bs[(kq << 2) + 0][col] = vb.x; Bs[(kq << 2) + 1][col] = vb.y;
        Bs[(kq << 2) + 2][col] = vb.z; Bs[(kq << 2) + 3][col] = vb.w;
      }
      __syncthreads();
      #pragma unroll
      for (int kk = 0; kk < 32; ++kk) {
        float2 a = *(const float2*)&As[kk][tm << 1];
        float4 b = *(const float4*)&Bs[kk][tu << 2];
        acc[0][0] = fmaf(a.x, b.x, acc[0][0]); acc[0][1] = fmaf(a.x, b.y, acc[0][1]);
        acc[0][2] = fmaf(a.x, b.z, acc[0][2]); acc[0][3] = fmaf(a.x, b.w, acc[0][3]);
        acc[1][0] = fmaf(a.y, b.x, acc[1][0]); acc[1][1] = fmaf(a.y, b.y, acc[1][1]);
        acc[1][2] = fmaf(a.y, b.z, acc[1][2]); acc[1][3] = fmaf(a.y, b.w, acc[1][3]);
      }
      __syncthreads();
    }
  }

  // recurrent part: h_in @ Whh^T, K = H = 512
  for (int k0 = 0; k0 < Hc; k0 += 32) {
    {
      int kq = tid & 7, m = tid >> 3;
      float4 va = *(const float4*)&h_in[(size_t)(b0 + m) * Hc + k0 + (kq << 2)];
      As[(kq << 2) + 0][m] = va.x; As[(kq << 2) + 1][m] = va.y;
      As[(kq << 2) + 2][m] = va.z; As[(kq << 2) + 3][m] = va.w;
    }
    #pragma unroll
    for (int i = 0; i < 2; ++i) {
      int lin = tid + (i << 8);
      int kq = lin & 7, u = (lin >> 3) & 15, g = (lin >> 7) & 3;
      float4 vb = *(const float4*)&Whh[(size_t)((g << 9) + u0 + u) * Hc + k0 + (kq << 2)];
      int col = (u << 2) + g;
      Bs[(kq << 2) + 0][col] = vb.x; Bs[(kq << 2) + 1][col] = vb.y;
      Bs[(kq << 2) + 2][col] = vb.z; Bs[(kq << 2) + 3][col] = vb.w;
    }
    __syncthreads();
    #pragma unroll
    for (int kk = 0; kk < 32; ++kk) {
      float2 a = *(const float2*)&As[kk][tm << 1];
      float4 b = *(const float4*)&Bs[kk][tu << 2];
      acc[0][0] = fmaf(a.x, b.x, acc[0][0]); acc[0][1] = fmaf(a.x, b.y, acc[0][1]);
      acc[0][2] = fmaf(a.x, b.z, acc[0][2]); acc[0][3] = fmaf(a.x, b.w, acc[0][3]);
      acc[1][0] = fmaf(a.y, b.x, acc[1][0]); acc[1][1] = fmaf(a.y, b.y, acc[1][1]);
      acc[1][2] = fmaf(a.y, b.z, acc[1][2]); acc[1][3] = fmaf(a.y, b.w, acc[1][3]);
    }
    __syncthreads();
  }

  const int u = u0 + tu;
  const float bi0 = bih[u]           + bhh[u];
  const float bf0 = bih[Hc + u]      + bhh[Hc + u];
  const float bg0 = bih[2 * Hc + u]  + bhh[2 * Hc + u];
  const float bo0 = bih[3 * Hc + u]  + bhh[3 * Hc + u];

  #pragma unroll
  for (int p = 0; p < 2; ++p) {
    const int b = b0 + (tm << 1) + p;
    float xi = 0.f, xf = 0.f, xg = 0.f, xo = 0.f;
    if (HAS_XPROJ) {
      int id = (idsB != nullptr && b >= BATCH) ? idsB[(b - BATCH) * T + t]
                                               : idsA[b * T + t];
      const float* xp = xproj_or_emb + (size_t)id * (4 * Hc);
      xi = xp[u]; xf = xp[Hc + u]; xg = xp[2 * Hc + u]; xo = xp[3 * Hc + u];
    }
    float gi = sigf(acc[p][0] + xi + bi0);
    float gf = sigf(acc[p][1] + xf + bf0);
    float gg = tanhf(acc[p][2] + xg + bg0);
    float go = sigf(acc[p][3] + xo + bo0);
    float c_old = c_in[(size_t)b * Hc + u];
    float cn = gf * c_old + gi * gg;
    float hn = go * tanhf(cn);
    c_out[(size_t)b * Hc + u] = cn;
    h_out[(size_t)b * Hc + u] = hn;
    if (feat) feat[((size_t)b * T + t) * Hc + u] = tanhf(hn);
    if (finals) {
      int len = (b < BATCH) ? lenA[b] : lenB[b - BATCH];
      if (t == len - 1) finals[(size_t)b * Hc + u] = tanhf(hn);
    }
  }
}

__global__ __launch_bounds__(256) void score_reduce_kernel(
    const float* __restrict__ scorep, const float* __restrict__ attnS_b,
    float* __restrict__ scores, int M, int nb)
{
  int r = blockIdx.x * 256 + threadIdx.x;
  if (r < M) {
    float s = attnS_b[0];
    for (int q = 0; q < nb; ++q) s += scorep[(size_t)q * M + r];
    scores[r] = s;
  }
}

__global__ __launch_bounds__(256) void softmax_pool_kernel(
    const float* __restrict__ scores, const int* __restrict__ tok_len,
    const float* __restrict__ feat, float* __restrict__ pooled)
{
  const int b = blockIdx.x;
  const int tid = threadIdx.x;
  __shared__ float w[TCc];
  __shared__ float red[256];
  const int len = tok_len[b];

  float myv = -1e30f;
  if (tid < TCc) {
    float s = scores[b * TCc + tid];
    myv = (tid < len) ? s : -1e9f;
    w[tid] = myv;
  }
  red[tid] = myv;
  __syncthreads();
  for (int s = 128; s > 0; s >>= 1) {
    if (tid < s) red[tid] = fmaxf(red[tid], red[tid + s]);
    __syncthreads();
  }
  const float mx = red[0];
  __syncthreads();
  float e = 0.f;
  if (tid < TCc) e = expf(w[tid] - mx);
  red[tid] = e;
  __syncthreads();
  for (int s = 128; s > 0; s >>= 1) {
    if (tid < s) red[tid] += red[tid + s];
    __syncthreads();
  }
  const float sum = red[0];
  __syncthreads();
  if (tid < TCc) w[tid] = e / sum;
  __syncthreads();

  for (int h = tid; h < Hc; h += 256) {
    float acc = 0.f;
    for (int t = 0; t < TCc; ++t)
      acc = fmaf(w[t], feat[((size_t)b * TCc + t) * Hc + h], acc);
    pooled[(size_t)b * Hc + h] = acc;
  }
}

__global__ __launch_bounds__(256) void loss_kernel(
    const float* __restrict__ code, const float* __restrict__ finals, float* __restrict__ out)
{
  const int b = threadIdx.x;
  const float* cv = code + (size_t)b * Hc;
  const float* av = finals + (size_t)b * Hc;
  const float* nv = finals + (size_t)(BATCH + b) * Hc;
  float dca = 0, dcn = 0, ncc = 0, naa = 0, nnn = 0;
  for (int k = 0; k < Hc; ++k) {
    float c = cv[k], a = av[k], n = nv[k];
    dca = fmaf(c, a, dca);
    dcn = fmaf(c, n, dcn);
    ncc = fmaf(c, c, ncc);
    naa = fmaf(a, a, naa);
    nnn = fmaf(n, n, nnn);
  }
  float cos_a = dca / fmaxf(sqrtf(ncc) * sqrtf(naa), 1e-8f);
  float cos_n = dcn / fmaxf(sqrtf(ncc) * sqrtf(nnn), 1e-8f);
  float hinge = fmaxf(0.6f - cos_a + cos_n, 1e-6f);
  __shared__ float red[256];
  red[b] = hinge;
  __syncthreads();
  for (int s = 128; s > 0; s >>= 1) {
    if (b < s) red[b] += red[b + s];
    __syncthreads();
  }
  if (b == 0) out[0] = red[0] / 256.0f;
}

extern "C" void kernel_launch(void* const* d_in, const int* in_sizes, int n_in,
                              void* d_out, int out_size, void* d_ws, size_t ws_size,
                              hipStream_t stream) {
  const int* tokens          = (const int*)d_in[0];
  const int* tok_len         = (const int*)d_in[1];
  const int* desc_anchor     = (const int*)d_in[2];
  const int* desc_anchor_len = (const int*)d_in[3];
  const int* desc_neg        = (const int*)d_in[4];
  const int* desc_neg_len    = (const int*)d_in[5];
  const float* tok_emb  = (const float*)d_in[6];
  const float* tok_Wih  = (const float*)d_in[7];
  const float* tok_Whh  = (const float*)d_in[8];
  const float* tok_bih  = (const float*)d_in[9];
  const float* tok_bhh  = (const float*)d_in[10];
  const float* desc_emb = (const float*)d_in[11];
  const float* desc_Wih = (const float*)d_in[12];
  const float* desc_Whh = (const float*)d_in[13];
  const float* desc_bih = (const float*)d_in[14];
  const float* desc_bhh = (const float*)d_in[15];
  const float* attn_W   = (const float*)d_in[16];
  const float* attn_b   = (const float*)d_in[17];
  const float* attnS_W  = (const float*)d_in[18];
  const float* attnS_b  = (const float*)d_in[19];
  const float* out_W1   = (const float*)d_in[20];
  const float* out_b1   = (const float*)d_in[21];
  const float* out_W2   = (const float*)d_in[22];
  const float* out_b2   = (const float*)d_in[23];

  const size_t BH = (size_t)BATCH * Hc;             // 131072
  const size_t f_feat = (size_t)BATCH * TCc * Hc;   // 26,214,400
  const size_t f_proj = (size_t)VOC * 4 * Hc;       // 20,480,000
  const size_t f_rest = 4 * BH + 8 * BH + 2 * BH + 8 * (size_t)BATCH * TCc
                      + (size_t)BATCH * TCc + 3 * BH;
  const size_t need_proj = (f_feat + 2 * f_proj + f_rest) * 4;
  const bool use_proj = (ws_size >= need_proj);

  float* p = (float*)d_ws;
  size_t off = 0;
  auto alloc = [&](size_t n) { float* q = p + off; off += n; return q; };

  float* feat = alloc(f_feat);
  float* tokproj = nullptr;
  float* descproj = nullptr;
  if (use_proj) { tokproj = alloc(f_proj); descproj = alloc(f_proj); }
  float* h_tok0  = alloc(BH);
  float* c_tok0  = alloc(BH);
  float* h_desc0 = alloc(2 * BH);
  float* c_desc0 = alloc(2 * BH);
  float* h_tok1  = alloc(BH);
  float* c_tok1  = alloc(BH);
  float* h_desc1 = alloc(2 * BH);
  float* c_desc1 = alloc(2 * BH);
  float* finals  = alloc(2 * BH);
  float* scorep  = alloc(8 * (size_t)BATCH * TCc);
  float* scores  = alloc((size_t)BATCH * TCc);
  float* pooled  = alloc(BH);
  float* a2      = alloc(BH);
  float* code    = alloc(BH);

  // zero initial states (h_tok0,c_tok0,h_desc0,c_desc0 are contiguous)
  const int zn = (int)(6 * BH);
  zero_kernel<<<(zn + 255) / 256, 256, 0, stream>>>(h_tok0, zn);

  if (use_proj) {
    dim3 gp((VOC + 63) / 64, (4 * Hc) / 64);  // (157, 32)
    gemm64_kernel<0, 0><<<gp, 256, 0, stream>>>(
        tok_emb, tok_Wih, nullptr, tokproj, nullptr, nullptr, VOC, 4 * Hc, Ec);
    gemm64_kernel<0, 0><<<gp, 256, 0, stream>>>(
        desc_emb, desc_Wih, nullptr, descproj, nullptr, nullptr, VOC, 4 * Hc, Ec);
  }

  // token LSTM: 200 sequential steps
  for (int t = 0; t < TCc; ++t) {
    float* hi = (t & 1) ? h_tok1 : h_tok0;
    float* ho = (t & 1) ? h_tok0 : h_tok1;
    float* ci = (t & 1) ? c_tok1 : c_tok0;
    float* co = (t & 1) ? c_tok0 : c_tok1;
    dim3 g(BATCH / 32, Hc / 16);
    if (use_proj)
      lstm_step2_kernel<1><<<g, 256, 0, stream>>>(
          tokproj, tok_Wih, tokens, nullptr, TCc, t, tok_Whh, tok_bih, tok_bhh,
          hi, ci, ho, co, feat, nullptr, nullptr, nullptr);
    else
      lstm_step2_kernel<0><<<g, 256, 0, stream>>>(
          tok_emb, tok_Wih, tokens, nullptr, TCc, t, tok_Whh, tok_bih, tok_bhh,
          hi, ci, ho, co, feat, nullptr, nullptr, nullptr);
  }

  // desc LSTM: anchor (rows 0..255) + neg (rows 256..511)
  for (int t = 0; t < TDc; ++t) {
    float* hi = (t & 1) ? h_desc1 : h_desc0;
    float* ho = (t & 1) ? h_desc0 : h_desc1;
    float* ci = (t & 1) ? c_desc1 : c_desc0;
    float* co = (t & 1) ? c_desc0 : c_desc1;
    dim3 g(2 * BATCH / 32, Hc / 16);
    if (use_proj)
      lstm_step2_kernel<1><<<g, 256, 0, stream>>>(
          descproj, desc_Wih, desc_anchor, desc_neg, TDc, t, desc_Whh, desc_bih, desc_bhh,
          hi, ci, ho, co, nullptr, finals, desc_anchor_len, desc_neg_len);
    else
      lstm_step2_kernel<0><<<g, 256, 0, stream>>>(
          desc_emb, desc_Wih, desc_anchor, desc_neg, TDc, t, desc_Whh, desc_bih, desc_bhh,
          hi, ci, ho, co, nullptr, finals, desc_anchor_len, desc_neg_len);
  }

  // attention scores: partial = tanh(feat @ attn_W^T + attn_b) . attnS_W  (per 64-col block)
  {
    dim3 ga((BATCH * TCc) / 64, Hc / 64);  // (800, 8)
    gemm64_kernel<1, 1><<<ga, 256, 0, stream>>>(
        feat, attn_W, attn_b, nullptr, attnS_W, scorep, BATCH * TCc, Hc, Hc);
    score_reduce_kernel<<<(BATCH * TCc + 255) / 256, 256, 0, stream>>>(
        scorep, attnS_b, scores, BATCH * TCc, Hc / 64);
  }

  softmax_pool_kernel<<<BATCH, 256, 0, stream>>>(scores, tok_len, feat, pooled);

  {
    dim3 go(BATCH / 64, Hc / 64);  // (4, 8)
    gemm64_kernel<1, 0><<<go, 256, 0, stream>>>(
        pooled, out_W1, out_b1, a2, nullptr, nullptr, BATCH, Hc, Hc);
    gemm64_kernel<1, 0><<<go, 256, 0, stream>>>(
        a2, out_W2, out_b2, code, nullptr, nullptr, BATCH, Hc, Hc);
  }

  loss_kernel<<<1, 256, 0, stream>>>(code, finals, (float*)d_out);
}

// Round 3
// 10196.601 us; speedup vs baseline: 2.2581x; 1.0009x over previous
//
#include <hip/hip_runtime.h>
#include <hip/hip_bf16.h>
#include <hip/hip_cooperative_groups.h>
#include <math.h>

namespace cg = cooperative_groups;

#define TCc 200
#define TDc 50
#define BATCH 256
#define Ec 300
#define Hc 512
#define VOC 10000

__device__ __forceinline__ float sigf(float x) { return 1.f / (1.f + expf(-x)); }

__global__ __launch_bounds__(256) void zero_kernel(float* p, int n) {
  int i = blockIdx.x * 256 + threadIdx.x;
  if (i < n) p[i] = 0.f;
}

// ---------------- generic 64x64-tile GEMM: out = act(A @ Bw^T + bias) ----------------
template<int ACT, int REDUCE>
__global__ __launch_bounds__(256) void gemm64_kernel(
    const float* __restrict__ A, const float* __restrict__ Bw,
    const float* __restrict__ bias, float* __restrict__ C,
    const float* __restrict__ sW, float* __restrict__ partial,
    int M, int N, int K)
{
  const int r0 = blockIdx.x * 64;
  const int n0 = blockIdx.y * 64;
  const int tid = threadIdx.x;
  const int tu = tid & 15;
  const int tm = tid >> 4;
  __shared__ float As[32][68];
  __shared__ float Bs[32][68];
  __shared__ float red[64][17];

  float acc[4][4] = {};
  const int nk = (K + 31) >> 5;
  for (int s = 0; s < nk; ++s) {
    const int k0 = s << 5;
    #pragma unroll
    for (int i = 0; i < 2; ++i) {
      int lin = tid + (i << 8);
      int kq = lin & 7, m = lin >> 3;
      int k = k0 + (kq << 2);
      int r = r0 + m; if (r >= M) r = M - 1;
      float4 va = {0.f, 0.f, 0.f, 0.f}, vb = {0.f, 0.f, 0.f, 0.f};
      if (k < K) {
        va = *(const float4*)&A[(size_t)r * K + k];
        vb = *(const float4*)&Bw[(size_t)(n0 + m) * K + k];
      }
      As[(kq << 2) + 0][m] = va.x; As[(kq << 2) + 1][m] = va.y;
      As[(kq << 2) + 2][m] = va.z; As[(kq << 2) + 3][m] = va.w;
      Bs[(kq << 2) + 0][m] = vb.x; Bs[(kq << 2) + 1][m] = vb.y;
      Bs[(kq << 2) + 2][m] = vb.z; Bs[(kq << 2) + 3][m] = vb.w;
    }
    __syncthreads();
    #pragma unroll
    for (int kk = 0; kk < 32; ++kk) {
      float4 a = *(const float4*)&As[kk][tm << 2];
      float4 b = *(const float4*)&Bs[kk][tu << 2];
      acc[0][0] = fmaf(a.x, b.x, acc[0][0]); acc[0][1] = fmaf(a.x, b.y, acc[0][1]);
      acc[0][2] = fmaf(a.x, b.z, acc[0][2]); acc[0][3] = fmaf(a.x, b.w, acc[0][3]);
      acc[1][0] = fmaf(a.y, b.x, acc[1][0]); acc[1][1] = fmaf(a.y, b.y, acc[1][1]);
      acc[1][2] = fmaf(a.y, b.z, acc[1][2]); acc[1][3] = fmaf(a.y, b.w, acc[1][3]);
      acc[2][0] = fmaf(a.z, b.x, acc[2][0]); acc[2][1] = fmaf(a.z, b.y, acc[2][1]);
      acc[2][2] = fmaf(a.z, b.z, acc[2][2]); acc[2][3] = fmaf(a.z, b.w, acc[2][3]);
      acc[3][0] = fmaf(a.w, b.x, acc[3][0]); acc[3][1] = fmaf(a.w, b.y, acc[3][1]);
      acc[3][2] = fmaf(a.w, b.z, acc[3][2]); acc[3][3] = fmaf(a.w, b.w, acc[3][3]);
    }
    __syncthreads();
  }

  if (REDUCE) {
    float bj[4], wj[4];
    #pragma unroll
    for (int j = 0; j < 4; ++j) {
      int n = n0 + (tu << 2) + j;
      bj[j] = bias[n]; wj[j] = sW[n];
    }
    float p[4] = {0.f, 0.f, 0.f, 0.f};
    #pragma unroll
    for (int i = 0; i < 4; ++i)
      #pragma unroll
      for (int j = 0; j < 4; ++j)
        p[i] = fmaf(tanhf(acc[i][j] + bj[j]), wj[j], p[i]);
    #pragma unroll
    for (int i = 0; i < 4; ++i) red[(tm << 2) + i][tu] = p[i];
    __syncthreads();
    if (tid < 64) {
      int r = r0 + tid;
      if (r < M) {
        float s = 0.f;
        #pragma unroll
        for (int q = 0; q < 16; ++q) s += red[tid][q];
        partial[(size_t)blockIdx.y * M + r] = s;
      }
    }
  } else {
    float bj[4];
    #pragma unroll
    for (int j = 0; j < 4; ++j) bj[j] = bias ? bias[n0 + (tu << 2) + j] : 0.f;
    #pragma unroll
    for (int i = 0; i < 4; ++i) {
      int r = r0 + (tm << 2) + i;
      if (r < M) {
        float4 v;
        v.x = acc[i][0] + bj[0]; v.y = acc[i][1] + bj[1];
        v.z = acc[i][2] + bj[2]; v.w = acc[i][3] + bj[3];
        if (ACT) { v.x = tanhf(v.x); v.y = tanhf(v.y); v.z = tanhf(v.z); v.w = tanhf(v.w); }
        *(float4*)&C[(size_t)r * N + n0 + (tu << 2)] = v;
      }
    }
  }
}

// ---------------- persistent cooperative LSTM ----------------
// 256 blocks = 8 row-groups x 32 col-groups (16 units each, 4 gates -> 64 weight cols).
// Whh slice LDS-resident (Ws[k][c], c=u*4+g, stride 68). c-state in registers.
// h ping-pongs via global; staged per 32-k chunk into hs[kk][row] with reg prefetch.
struct CoopArgs {
  const float* tokproj; const float* descproj;
  const int* tokens; const int* desc_anchor; const int* desc_neg;
  const int* desc_anchor_len; const int* desc_neg_len;
  const float* tok_Whh; const float* tok_bih; const float* tok_bhh;
  const float* desc_Whh; const float* desc_bih; const float* desc_bhh;
  float* h0; float* h1; float* feat; float* finals;
};

template<int ROWS, bool IS_TOK>
__device__ void lstm_phase(float* Ws, float* hs, cg::grid_group& grid,
    const float* __restrict__ xproj,
    const int* __restrict__ idsA, const int* __restrict__ idsB,
    const int* __restrict__ lenA, const int* __restrict__ lenB, int T,
    const float* __restrict__ Whh, const float* __restrict__ bih, const float* __restrict__ bhh,
    float* __restrict__ h0, float* __restrict__ h1,
    float* __restrict__ feat, float* __restrict__ finals)
{
  const int tid = threadIdx.x;
  const int bx = blockIdx.x;
  const int rg = bx >> 5;          // 8 row-groups
  const int u0 = (bx & 31) << 4;   // 32 col-groups x 16 units
  const int tu = tid & 15;
  const int tm = tid >> 4;
  constexpr int RP = ROWS / 16;    // rows per thread (2 or 4)
  constexpr int NLD = ROWS / 32;   // float4 stage-loads per thread (1 or 2)

  // ---- load Whh slice into LDS: Ws[k][c], c = u*4+g ----
  for (int it = 0; it < 32; ++it) {
    int idx = (it * 256 + tid) << 2;   // element index; k fastest
    int c = idx >> 9, k = idx & 511;
    int u = c >> 2, g = c & 3;
    float4 v = *(const float4*)&Whh[(((size_t)(g << 9) + u0 + u) << 9) + k];
    Ws[(k + 0) * 68 + c] = v.x;
    Ws[(k + 1) * 68 + c] = v.y;
    Ws[(k + 2) * 68 + c] = v.z;
    Ws[(k + 3) * 68 + c] = v.w;
  }
  __syncthreads();

  float bs[4];
  #pragma unroll
  for (int g = 0; g < 4; ++g)
    bs[g] = bih[(g << 9) + u0 + tu] + bhh[(g << 9) + u0 + tu];

  float cc[RP];
  #pragma unroll
  for (int p = 0; p < RP; ++p) cc[p] = 0.f;

  // zero this block's h0 partition
  #pragma unroll
  for (int p = 0; p < RP; ++p) {
    int row = rg * ROWS + tm * RP + p;
    h0[((size_t)row << 9) + u0 + tu] = 0.f;
  }
  __threadfence();
  grid.sync();

  for (int t = 0; t < T; ++t) {
    const float* hin = (t & 1) ? h1 : h0;
    float* hout = (t & 1) ? h0 : h1;
    float acc[RP][4] = {};
    float4 pre[NLD];
    #pragma unroll
    for (int l = 0; l < NLD; ++l) {
      int lin = (l << 8) + tid;
      int row = lin >> 3, kq = lin & 7;
      pre[l] = *(const float4*)&hin[((size_t)(rg * ROWS + row) << 9) + (kq << 2)];
    }
    for (int k0 = 0; k0 < Hc; k0 += 32) {
      #pragma unroll
      for (int l = 0; l < NLD; ++l) {
        int lin = (l << 8) + tid;
        int row = lin >> 3, kq = lin & 7;
        hs[((kq << 2) + 0) * 68 + row] = pre[l].x;
        hs[((kq << 2) + 1) * 68 + row] = pre[l].y;
        hs[((kq << 2) + 2) * 68 + row] = pre[l].z;
        hs[((kq << 2) + 3) * 68 + row] = pre[l].w;
      }
      __syncthreads();
      if (k0 < Hc - 32) {
        #pragma unroll
        for (int l = 0; l < NLD; ++l) {
          int lin = (l << 8) + tid;
          int row = lin >> 3, kq = lin & 7;
          pre[l] = *(const float4*)&hin[((size_t)(rg * ROWS + row) << 9) + k0 + 32 + (kq << 2)];
        }
      }
      #pragma unroll
      for (int kk = 0; kk < 32; ++kk) {
        float4 w = *(const float4*)&Ws[(k0 + kk) * 68 + (tu << 2)];
        if constexpr (RP == 2) {
          float2 a = *(const float2*)&hs[kk * 68 + (tm << 1)];
          acc[0][0] = fmaf(a.x, w.x, acc[0][0]); acc[0][1] = fmaf(a.x, w.y, acc[0][1]);
          acc[0][2] = fmaf(a.x, w.z, acc[0][2]); acc[0][3] = fmaf(a.x, w.w, acc[0][3]);
          acc[1][0] = fmaf(a.y, w.x, acc[1][0]); acc[1][1] = fmaf(a.y, w.y, acc[1][1]);
          acc[1][2] = fmaf(a.y, w.z, acc[1][2]); acc[1][3] = fmaf(a.y, w.w, acc[1][3]);
        } else {
          float4 a = *(const float4*)&hs[kk * 68 + (tm << 2)];
          acc[0][0] = fmaf(a.x, w.x, acc[0][0]); acc[0][1] = fmaf(a.x, w.y, acc[0][1]);
          acc[0][2] = fmaf(a.x, w.z, acc[0][2]); acc[0][3] = fmaf(a.x, w.w, acc[0][3]);
          acc[1][0] = fmaf(a.y, w.x, acc[1][0]); acc[1][1] = fmaf(a.y, w.y, acc[1][1]);
          acc[1][2] = fmaf(a.y, w.z, acc[1][2]); acc[1][3] = fmaf(a.y, w.w, acc[1][3]);
          acc[2][0] = fmaf(a.z, w.x, acc[2][0]); acc[2][1] = fmaf(a.z, w.y, acc[2][1]);
          acc[2][2] = fmaf(a.z, w.z, acc[2][2]); acc[2][3] = fmaf(a.z, w.w, acc[2][3]);
          acc[3][0] = fmaf(a.w, w.x, acc[3][0]); acc[3][1] = fmaf(a.w, w.y, acc[3][1]);
          acc[3][2] = fmaf(a.w, w.z, acc[3][2]); acc[3][3] = fmaf(a.w, w.w, acc[3][3]);
        }
      }
      __syncthreads();
    }
    // ---- epilogue: gather x-projection, gates, c/h update, outputs ----
    #pragma unroll
    for (int p = 0; p < RP; ++p) {
      int row = rg * ROWS + tm * RP + p;
      int id;
      if (IS_TOK) id = idsA[row * T + t];
      else id = (row < BATCH) ? idsA[row * T + t] : idsB[(row - BATCH) * T + t];
      const float* xp = xproj + ((size_t)id << 11);
      float gi = sigf(acc[p][0] + xp[u0 + tu] + bs[0]);
      float gf = sigf(acc[p][1] + xp[Hc + u0 + tu] + bs[1]);
      float gg = tanhf(acc[p][2] + xp[2 * Hc + u0 + tu] + bs[2]);
      float go = sigf(acc[p][3] + xp[3 * Hc + u0 + tu] + bs[3]);
      float cn = gf * cc[p] + gi * gg;
      cc[p] = cn;
      float hn = go * tanhf(cn);
      hout[((size_t)row << 9) + u0 + tu] = hn;
      if (IS_TOK) {
        feat[((size_t)row * TCc + t) * Hc + u0 + tu] = tanhf(hn);
      } else {
        int len = (row < BATCH) ? lenA[row] : lenB[row - BATCH];
        if (t == len - 1) finals[((size_t)row << 9) + u0 + tu] = tanhf(hn);
      }
    }
    __threadfence();
    grid.sync();
  }
}

__global__ void __launch_bounds__(256, 1) lstm_coop_kernel(CoopArgs A) {
  cg::grid_group grid = cg::this_grid();
  extern __shared__ float smem[];
  float* Ws = smem;                 // [512][68]
  float* hs = smem + 512 * 68;      // [32][68]
  lstm_phase<32, true>(Ws, hs, grid, A.tokproj, A.tokens, nullptr,
                       nullptr, nullptr, TCc,
                       A.tok_Whh, A.tok_bih, A.tok_bhh, A.h0, A.h1, A.feat, nullptr);
  lstm_phase<64, false>(Ws, hs, grid, A.descproj, A.desc_anchor, A.desc_neg,
                        A.desc_anchor_len, A.desc_neg_len, TDc,
                        A.desc_Whh, A.desc_bih, A.desc_bhh, A.h0, A.h1, nullptr, A.finals);
}

// ---------------- fallback per-step kernel (round-2) ----------------
template<int HAS_XPROJ>
__global__ __launch_bounds__(256) void lstm_step2_kernel(
    const float* __restrict__ xproj_or_emb, const float* __restrict__ Wih,
    const int* __restrict__ idsA, const int* __restrict__ idsB,
    int T, int t,
    const float* __restrict__ Whh,
    const float* __restrict__ bih, const float* __restrict__ bhh,
    const float* __restrict__ h_in, const float* __restrict__ c_in,
    float* __restrict__ h_out, float* __restrict__ c_out,
    float* __restrict__ feat, float* __restrict__ finals,
    const int* __restrict__ lenA, const int* __restrict__ lenB)
{
  const int b0 = blockIdx.x * 32;
  const int u0 = blockIdx.y * 16;
  const int tid = threadIdx.x;
  const int tu = tid & 15;
  const int tm = tid >> 4;

  __shared__ float As[32][34];
  __shared__ float Bs[32][68];
  __shared__ int rows[32];

  float acc[2][4] = {};

  if (!HAS_XPROJ) {
    if (tid < 32) {
      int b = b0 + tid;
      rows[tid] = (idsB != nullptr && b >= BATCH) ? idsB[(b - BATCH) * T + t]
                                                  : idsA[b * T + t];
    }
    __syncthreads();
    for (int k0 = 0; k0 < Ec; k0 += 32) {
      {
        int kq = tid & 7, m = tid >> 3;
        int k = k0 + (kq << 2);
        float4 va = {0.f, 0.f, 0.f, 0.f};
        if (k < Ec) va = *(const float4*)&xproj_or_emb[(size_t)rows[m] * Ec + k];
        As[(kq << 2) + 0][m] = va.x; As[(kq << 2) + 1][m] = va.y;
        As[(kq << 2) + 2][m] = va.z; As[(kq << 2) + 3][m] = va.w;
      }
      #pragma unroll
      for (int i = 0; i < 2; ++i) {
        int lin = tid + (i << 8);
        int kq = lin & 7, u = (lin >> 3) & 15, g = (lin >> 7) & 3;
        int k = k0 + (kq << 2);
        float4 vb = {0.f, 0.f, 0.f, 0.f};
        if (k < Ec) vb = *(const float4*)&Wih[(size_t)((g << 9) + u0 + u) * Ec + k];
        int col = (u << 2) + g;
        Bs[(kq << 2) + 0][col] = vb.x; Bs[(kq << 2) + 1][col] = vb.y;
        Bs[(kq << 2) + 2][col] = vb.z; Bs[(kq << 2) + 3][col] = vb.w;
      }
      __syncthreads();
      #pragma unroll
      for (int kk = 0; kk < 32; ++kk) {
        float2 a = *(const float2*)&As[kk][tm << 1];
        float4 b = *(const float4*)&Bs[kk][tu << 2];
        acc[0][0] = fmaf(a.x, b.x, acc[0][0]); acc[0][1] = fmaf(a.x, b.y, acc[0][1]);
        acc[0][2] = fmaf(a.x, b.z, acc[0][2]); acc[0][3] = fmaf(a.x, b.w, acc[0][3]);
        acc[1][0] = fmaf(a.y, b.x, acc[1][0]); acc[1][1] = fmaf(a.y, b.y, acc[1][1]);
        acc[1][2] = fmaf(a.y, b.z, acc[1][2]); acc[1][3] = fmaf(a.y, b.w, acc[1][3]);
      }
      __syncthreads();
    }
  }

  for (int k0 = 0; k0 < Hc; k0 += 32) {
    {
      int kq = tid & 7, m = tid >> 3;
      float4 va = *(const float4*)&h_in[(size_t)(b0 + m) * Hc + k0 + (kq << 2)];
      As[(kq << 2) + 0][m] = va.x; As[(kq << 2) + 1][m] = va.y;
      As[(kq << 2) + 2][m] = va.z; As[(kq << 2) + 3][m] = va.w;
    }
    #pragma unroll
    for (int i = 0; i < 2; ++i) {
      int lin = tid + (i << 8);
      int kq = lin & 7, u = (lin >> 3) & 15, g = (lin >> 7) & 3;
      float4 vb = *(const float4*)&Whh[(size_t)((g << 9) + u0 + u) * Hc + k0 + (kq << 2)];
      int col = (u << 2) + g;
      Bs[(kq << 2) + 0][col] = vb.x; Bs[(kq << 2) + 1][col] = vb.y;
      Bs[(kq << 2) + 2][col] = vb.z; Bs[(kq << 2) + 3][col] = vb.w;
    }
    __syncthreads();
    #pragma unroll
    for (int kk = 0; kk < 32; ++kk) {
      float2 a = *(const float2*)&As[kk][tm << 1];
      float4 b = *(const float4*)&Bs[kk][tu << 2];
      acc[0][0] = fmaf(a.x, b.x, acc[0][0]); acc[0][1] = fmaf(a.x, b.y, acc[0][1]);
      acc[0][2] = fmaf(a.x, b.z, acc[0][2]); acc[0][3] = fmaf(a.x, b.w, acc[0][3]);
      acc[1][0] = fmaf(a.y, b.x, acc[1][0]); acc[1][1] = fmaf(a.y, b.y, acc[1][1]);
      acc[1][2] = fmaf(a.y, b.z, acc[1][2]); acc[1][3] = fmaf(a.y, b.w, acc[1][3]);
    }
    __syncthreads();
  }

  const int u = u0 + tu;
  const float bi0 = bih[u]           + bhh[u];
  const float bf0 = bih[Hc + u]      + bhh[Hc + u];
  const float bg0 = bih[2 * Hc + u]  + bhh[2 * Hc + u];
  const float bo0 = bih[3 * Hc + u]  + bhh[3 * Hc + u];

  #pragma unroll
  for (int p = 0; p < 2; ++p) {
    const int b = b0 + (tm << 1) + p;
    float xi = 0.f, xf = 0.f, xg = 0.f, xo = 0.f;
    if (HAS_XPROJ) {
      int id = (idsB != nullptr && b >= BATCH) ? idsB[(b - BATCH) * T + t]
                                               : idsA[b * T + t];
      const float* xp = xproj_or_emb + (size_t)id * (4 * Hc);
      xi = xp[u]; xf = xp[Hc + u]; xg = xp[2 * Hc + u]; xo = xp[3 * Hc + u];
    }
    float gi = sigf(acc[p][0] + xi + bi0);
    float gf = sigf(acc[p][1] + xf + bf0);
    float gg = tanhf(acc[p][2] + xg + bg0);
    float go = sigf(acc[p][3] + xo + bo0);
    float c_old = c_in[(size_t)b * Hc + u];
    float cn = gf * c_old + gi * gg;
    float hn = go * tanhf(cn);
    c_out[(size_t)b * Hc + u] = cn;
    h_out[(size_t)b * Hc + u] = hn;
    if (feat) feat[((size_t)b * T + t) * Hc + u] = tanhf(hn);
    if (finals) {
      int len = (b < BATCH) ? lenA[b] : lenB[b - BATCH];
      if (t == len - 1) finals[(size_t)b * Hc + u] = tanhf(hn);
    }
  }
}

__global__ __launch_bounds__(256) void score_reduce_kernel(
    const float* __restrict__ scorep, const float* __restrict__ attnS_b,
    float* __restrict__ scores, int M, int nb)
{
  int r = blockIdx.x * 256 + threadIdx.x;
  if (r < M) {
    float s = attnS_b[0];
    for (int q = 0; q < nb; ++q) s += scorep[(size_t)q * M + r];
    scores[r] = s;
  }
}

__global__ __launch_bounds__(256) void softmax_pool_kernel(
    const float* __restrict__ scores, const int* __restrict__ tok_len,
    const float* __restrict__ feat, float* __restrict__ pooled)
{
  const int b = blockIdx.x;
  const int tid = threadIdx.x;
  __shared__ float w[TCc];
  __shared__ float red[256];
  const int len = tok_len[b];

  float myv = -1e30f;
  if (tid < TCc) {
    float s = scores[b * TCc + tid];
    myv = (tid < len) ? s : -1e9f;
    w[tid] = myv;
  }
  red[tid] = myv;
  __syncthreads();
  for (int s = 128; s > 0; s >>= 1) {
    if (tid < s) red[tid] = fmaxf(red[tid], red[tid + s]);
    __syncthreads();
  }
  const float mx = red[0];
  __syncthreads();
  float e = 0.f;
  if (tid < TCc) e = expf(w[tid] - mx);
  red[tid] = e;
  __syncthreads();
  for (int s = 128; s > 0; s >>= 1) {
    if (tid < s) red[tid] += red[tid + s];
    __syncthreads();
  }
  const float sum = red[0];
  __syncthreads();
  if (tid < TCc) w[tid] = e / sum;
  __syncthreads();

  for (int h = tid; h < Hc; h += 256) {
    float acc = 0.f;
    for (int t = 0; t < TCc; ++t)
      acc = fmaf(w[t], feat[((size_t)b * TCc + t) * Hc + h], acc);
    pooled[(size_t)b * Hc + h] = acc;
  }
}

__global__ __launch_bounds__(256) void loss_kernel(
    const float* __restrict__ code, const float* __restrict__ finals, float* __restrict__ out)
{
  const int b = threadIdx.x;
  const float* cv = code + (size_t)b * Hc;
  const float* av = finals + (size_t)b * Hc;
  const float* nv = finals + (size_t)(BATCH + b) * Hc;
  float dca = 0, dcn = 0, ncc = 0, naa = 0, nnn = 0;
  for (int k = 0; k < Hc; ++k) {
    float c = cv[k], a = av[k], n = nv[k];
    dca = fmaf(c, a, dca);
    dcn = fmaf(c, n, dcn);
    ncc = fmaf(c, c, ncc);
    naa = fmaf(a, a, naa);
    nnn = fmaf(n, n, nnn);
  }
  float cos_a = dca / fmaxf(sqrtf(ncc) * sqrtf(naa), 1e-8f);
  float cos_n = dcn / fmaxf(sqrtf(ncc) * sqrtf(nnn), 1e-8f);
  float hinge = fmaxf(0.6f - cos_a + cos_n, 1e-6f);
  __shared__ float red[256];
  red[b] = hinge;
  __syncthreads();
  for (int s = 128; s > 0; s >>= 1) {
    if (b < s) red[b] += red[b + s];
    __syncthreads();
  }
  if (b == 0) out[0] = red[0] / 256.0f;
}

extern "C" void kernel_launch(void* const* d_in, const int* in_sizes, int n_in,
                              void* d_out, int out_size, void* d_ws, size_t ws_size,
                              hipStream_t stream) {
  const int* tokens          = (const int*)d_in[0];
  const int* tok_len         = (const int*)d_in[1];
  const int* desc_anchor     = (const int*)d_in[2];
  const int* desc_anchor_len = (const int*)d_in[3];
  const int* desc_neg        = (const int*)d_in[4];
  const int* desc_neg_len    = (const int*)d_in[5];
  const float* tok_emb  = (const float*)d_in[6];
  const float* tok_Wih  = (const float*)d_in[7];
  const float* tok_Whh  = (const float*)d_in[8];
  const float* tok_bih  = (const float*)d_in[9];
  const float* tok_bhh  = (const float*)d_in[10];
  const float* desc_emb = (const float*)d_in[11];
  const float* desc_Wih = (const float*)d_in[12];
  const float* desc_Whh = (const float*)d_in[13];
  const float* desc_bih = (const float*)d_in[14];
  const float* desc_bhh = (const float*)d_in[15];
  const float* attn_W   = (const float*)d_in[16];
  const float* attn_b   = (const float*)d_in[17];
  const float* attnS_W  = (const float*)d_in[18];
  const float* attnS_b  = (const float*)d_in[19];
  const float* out_W1   = (const float*)d_in[20];
  const float* out_b1   = (const float*)d_in[21];
  const float* out_W2   = (const float*)d_in[22];
  const float* out_b2   = (const float*)d_in[23];

  const size_t BH = (size_t)BATCH * Hc;
  const size_t f_feat = (size_t)BATCH * TCc * Hc;
  const size_t f_proj = (size_t)VOC * 4 * Hc;
  const size_t f_total = f_feat + 2 * f_proj + 2 * (2 * BH) + 12 * BH + 2 * BH
                       + 8 * (size_t)BATCH * TCc + (size_t)BATCH * TCc + 3 * BH;
  const bool use_proj = (ws_size >= f_total * 4);

  float* p = (float*)d_ws;
  size_t off = 0;
  auto alloc = [&](size_t n) { float* q = p + off; off += n; return q; };

  float* feat = alloc(f_feat);
  float* tokproj = nullptr;
  float* descproj = nullptr;
  if (use_proj) { tokproj = alloc(f_proj); descproj = alloc(f_proj); }
  float* hA = alloc(2 * BH);   // coop h ping (512 rows)
  float* hB = alloc(2 * BH);   // coop h pong
  float* h_tok0  = alloc(BH);  // fallback buffers
  float* c_tok0  = alloc(BH);
  float* h_desc0 = alloc(2 * BH);
  float* c_desc0 = alloc(2 * BH);
  float* h_tok1  = alloc(BH);
  float* c_tok1  = alloc(BH);
  float* h_desc1 = alloc(2 * BH);
  float* c_desc1 = alloc(2 * BH);
  float* finals  = alloc(2 * BH);
  float* scorep  = alloc(8 * (size_t)BATCH * TCc);
  float* scores  = alloc((size_t)BATCH * TCc);
  float* pooled  = alloc(BH);
  float* a2      = alloc(BH);
  float* code    = alloc(BH);

  if (use_proj) {
    dim3 gp((VOC + 63) / 64, (4 * Hc) / 64);
    gemm64_kernel<0, 0><<<gp, 256, 0, stream>>>(
        tok_emb, tok_Wih, nullptr, tokproj, nullptr, nullptr, VOC, 4 * Hc, Ec);
    gemm64_kernel<0, 0><<<gp, 256, 0, stream>>>(
        desc_emb, desc_Wih, nullptr, descproj, nullptr, nullptr, VOC, 4 * Hc, Ec);
  }

  bool coop_done = false;
  if (use_proj) {
    const unsigned smem_bytes = (512 * 68 + 32 * 68) * 4;  // 147,968 B
    hipFuncSetAttribute((const void*)lstm_coop_kernel,
                        hipFuncAttributeMaxDynamicSharedMemorySize, smem_bytes);
    CoopArgs ca;
    ca.tokproj = tokproj; ca.descproj = descproj;
    ca.tokens = tokens; ca.desc_anchor = desc_anchor; ca.desc_neg = desc_neg;
    ca.desc_anchor_len = desc_anchor_len; ca.desc_neg_len = desc_neg_len;
    ca.tok_Whh = tok_Whh; ca.tok_bih = tok_bih; ca.tok_bhh = tok_bhh;
    ca.desc_Whh = desc_Whh; ca.desc_bih = desc_bih; ca.desc_bhh = desc_bhh;
    ca.h0 = hA; ca.h1 = hB; ca.feat = feat; ca.finals = finals;
    void* kargs[] = { (void*)&ca };
    hipError_t e = hipLaunchCooperativeKernel((const void*)lstm_coop_kernel,
                                              dim3(256), dim3(256), kargs,
                                              smem_bytes, stream);
    coop_done = (e == hipSuccess);
  }

  if (!coop_done) {
    const int zn = (int)(6 * BH);
    zero_kernel<<<(zn + 255) / 256, 256, 0, stream>>>(h_tok0, zn);
    for (int t = 0; t < TCc; ++t) {
      float* hi = (t & 1) ? h_tok1 : h_tok0;
      float* ho = (t & 1) ? h_tok0 : h_tok1;
      float* ci = (t & 1) ? c_tok1 : c_tok0;
      float* co = (t & 1) ? c_tok0 : c_tok1;
      dim3 g(BATCH / 32, Hc / 16);
      if (use_proj)
        lstm_step2_kernel<1><<<g, 256, 0, stream>>>(
            tokproj, tok_Wih, tokens, nullptr, TCc, t, tok_Whh, tok_bih, tok_bhh,
            hi, ci, ho, co, feat, nullptr, nullptr, nullptr);
      else
        lstm_step2_kernel<0><<<g, 256, 0, stream>>>(
            tok_emb, tok_Wih, tokens, nullptr, TCc, t, tok_Whh, tok_bih, tok_bhh,
            hi, ci, ho, co, feat, nullptr, nullptr, nullptr);
    }
    for (int t = 0; t < TDc; ++t) {
      float* hi = (t & 1) ? h_desc1 : h_desc0;
      float* ho = (t & 1) ? h_desc0 : h_desc1;
      float* ci = (t & 1) ? c_desc1 : c_desc0;
      float* co = (t & 1) ? c_desc0 : c_desc1;
      dim3 g(2 * BATCH / 32, Hc / 16);
      if (use_proj)
        lstm_step2_kernel<1><<<g, 256, 0, stream>>>(
            descproj, desc_Wih, desc_anchor, desc_neg, TDc, t, desc_Whh, desc_bih, desc_bhh,
            hi, ci, ho, co, nullptr, finals, desc_anchor_len, desc_neg_len);
      else
        lstm_step2_kernel<0><<<g, 256, 0, stream>>>(
            desc_emb, desc_Wih, desc_anchor, desc_neg, TDc, t, desc_Whh, desc_bih, desc_bhh,
            hi, ci, ho, co, nullptr, finals, desc_anchor_len, desc_neg_len);
    }
  }

  {
    dim3 ga((BATCH * TCc) / 64, Hc / 64);
    gemm64_kernel<1, 1><<<ga, 256, 0, stream>>>(
        feat, attn_W, attn_b, nullptr, attnS_W, scorep, BATCH * TCc, Hc, Hc);
    score_reduce_kernel<<<(BATCH * TCc + 255) / 256, 256, 0, stream>>>(
        scorep, attnS_b, scores, BATCH * TCc, Hc / 64);
  }

  softmax_pool_kernel<<<BATCH, 256, 0, stream>>>(scores, tok_len, feat, pooled);

  {
    dim3 go(BATCH / 64, Hc / 64);
    gemm64_kernel<1, 0><<<go, 256, 0, stream>>>(
        pooled, out_W1, out_b1, a2, nullptr, nullptr, BATCH, Hc, Hc);
    gemm64_kernel<1, 0><<<go, 256, 0, stream>>>(
        a2, out_W2, out_b2, code, nullptr, nullptr, BATCH, Hc, Hc);
  }

  loss_kernel<<<1, 256, 0, stream>>>(code, finals, (float*)d_out);
}